// Round 13
// baseline (168.796 us; speedup 1.0000x reference)
//
#include <hip/hip_runtime.h>
#include <hip/hip_bf16.h>

#define TOT     2048      // B*SEQ rows
#define INDIM   512
#define OD      256
#define SEQL    1024
#define TQ      512       // out_seq
#define NB      2
#define LN_EPS  1e-5f

#define JSPL    16        // k2 j-split (planes)
#define JW      (OD / JSPL)      // 16 j per k2 block
#define K3SPL   4         // k3 K-split

typedef __attribute__((ext_vector_type(8))) short bf16x8;
typedef __attribute__((ext_vector_type(4))) float f32x4;
typedef __attribute__((ext_vector_type(2))) float f32x2;

__device__ __forceinline__ short f2bf(float f) {
    __hip_bfloat16 h = __float2bfloat16(f);
    return *(short*)&h;
}
__device__ __forceinline__ uint pack2(float a, float b) {
    return (uint)(ushort)f2bf(a) | ((uint)(ushort)f2bf(b) << 16);
}
__device__ __forceinline__ float bflo(uint t) { return __uint_as_float(t << 16); }
__device__ __forceinline__ float bfhi(uint t) { return __uint_as_float(t & 0xFFFF0000u); }

// ============ shared 64x64 MFMA tile: C = A[rows][k] * B[cols][k]^T ============
// CVT: operands are f32 in global, converted to bf16 during LDS staging.
template<bool CVT>
__device__ __forceinline__ void mfma_tile64(
    const void* __restrict__ Av, int lda,
    const void* __restrict__ Bv, int ldb,
    float* __restrict__ C, int ldc,
    int r0, int c0, int k0, int nk)
{
    __shared__ short Al[64][40];   // pad to 40 bf16 (80 B rows, 16B-aligned)
    __shared__ short Bl[64][40];
    const int tid = threadIdx.x;
    const int w   = tid >> 6;
    const int wm  = w >> 1, wn = w & 1;
    const int l   = tid & 63;
    const int lr  = l & 15, lg = l >> 4;
    const int srow = tid >> 2, skg = (tid & 3) * 8;

    f32x4 acc[2][2] = {{{0.f,0.f,0.f,0.f},{0.f,0.f,0.f,0.f}},
                       {{0.f,0.f,0.f,0.f},{0.f,0.f,0.f,0.f}}};

    for (int ks = 0; ks < nk; ++ks) {
        const int kb = k0 + ks * 32;
        __syncthreads();
        if (CVT) {
            const float* Af = (const float*)Av;
            const float* Bf = (const float*)Bv;
            const float* ar = Af + (size_t)(r0 + srow) * lda + kb + skg;
            float4 a0 = *(const float4*)ar, a1 = *(const float4*)(ar + 4);
            *(uint4*)&Al[srow][skg] = make_uint4(pack2(a0.x, a0.y), pack2(a0.z, a0.w),
                                                 pack2(a1.x, a1.y), pack2(a1.z, a1.w));
            const float* br = Bf + (size_t)(c0 + srow) * ldb + kb + skg;
            float4 b0 = *(const float4*)br, b1 = *(const float4*)(br + 4);
            *(uint4*)&Bl[srow][skg] = make_uint4(pack2(b0.x, b0.y), pack2(b0.z, b0.w),
                                                 pack2(b1.x, b1.y), pack2(b1.z, b1.w));
        } else {
            const short* As = (const short*)Av;
            const short* Bs = (const short*)Bv;
            *(bf16x8*)&Al[srow][skg] = *(const bf16x8*)(As + (size_t)(r0 + srow) * lda + kb + skg);
            *(bf16x8*)&Bl[srow][skg] = *(const bf16x8*)(Bs + (size_t)(c0 + srow) * ldb + kb + skg);
        }
        __syncthreads();
        bf16x8 a0 = *(const bf16x8*)&Al[wm * 32 +      lr][lg * 8];
        bf16x8 a1 = *(const bf16x8*)&Al[wm * 32 + 16 + lr][lg * 8];
        bf16x8 b0 = *(const bf16x8*)&Bl[wn * 32 +      lr][lg * 8];
        bf16x8 b1 = *(const bf16x8*)&Bl[wn * 32 + 16 + lr][lg * 8];
        acc[0][0] = __builtin_amdgcn_mfma_f32_16x16x32_bf16(a0, b0, acc[0][0], 0, 0, 0);
        acc[0][1] = __builtin_amdgcn_mfma_f32_16x16x32_bf16(a0, b1, acc[0][1], 0, 0, 0);
        acc[1][0] = __builtin_amdgcn_mfma_f32_16x16x32_bf16(a1, b0, acc[1][0], 0, 0, 0);
        acc[1][1] = __builtin_amdgcn_mfma_f32_16x16x32_bf16(a1, b1, acc[1][1], 0, 0, 0);
    }
    // D: col = lane&15, row = 4*(lane>>4)+reg  [m89-verified]
#pragma unroll
    for (int sm = 0; sm < 2; ++sm)
#pragma unroll
    for (int sn = 0; sn < 2; ++sn)
#pragma unroll
    for (int q = 0; q < 4; ++q)
        C[(size_t)(r0 + wm * 32 + sm * 16 + 4 * lg + q) * ldc
          + (c0 + wn * 32 + sn * 16 + lr)] = acc[sm][sn][q];
}

// ============ K1: Zp[h] = bf16(x)*bf16(M)^T; last-of-8 per stripe -> LN stats ============
__global__ __launch_bounds__(256, 4) void k1_mfma(
    const float* __restrict__ x, const float* __restrict__ M,
    float* __restrict__ Zp, float* __restrict__ muv, float* __restrict__ inv,
    int* __restrict__ cnt)
{
    mfma_tile64<true>(x, INDIM, M, INDIM,
                      Zp + (size_t)blockIdx.z * TOT * OD, OD,
                      blockIdx.x * 64, blockIdx.y * 64, blockIdx.z * 256, 8);

    __threadfence();
    __syncthreads();
    __shared__ int lastf;
    if (threadIdx.x == 0)
        lastf = (atomicAdd(&cnt[blockIdx.x], 1) == 7);
    __syncthreads();
    if (!lastf) return;

    // LN stats for rows r0..r0+63 over all 256 cols (Zp0+Zp1)
    const int row  = blockIdx.x * 64 + (threadIdx.x >> 2);
    const int part = threadIdx.x & 3;
    const float* z0 = Zp + (size_t)row * OD + part * 64;
    const float* z1 = z0 + (size_t)TOT * OD;
    float s = 0.f, q = 0.f;
#pragma unroll 8
    for (int c = 0; c < 64; ++c) {
        float v = z0[c] + z1[c];
        s += v; q += v * v;
    }
    s += __shfl_xor(s, 1); q += __shfl_xor(q, 1);
    s += __shfl_xor(s, 2); q += __shfl_xor(q, 2);
    if (part == 0) {
        float m  = s * (1.f / OD);
        float vr = q * (1.f / OD) - m * m;
        muv[row] = m;
        inv[row] = rsqrtf(vr + LN_EPS);
    }
}

// ============ K2f: T planes (Chebyshev); last-of-16 per (k,i) tile -> W ============
// Zn applied on the fly during staging: zn = (Zp0+Zp1-mu)*inv*gamma+beta.
__global__ __launch_bounds__(128) void k2_t(
    const float* __restrict__ Zp, const float* __restrict__ muv, const float* __restrict__ inv,
    const float* __restrict__ gamma, const float* __restrict__ beta,
    const float* __restrict__ P, short* __restrict__ Tp,
    float* __restrict__ W, int* __restrict__ cnt)
{
    const int k0 = blockIdx.x * 64;
    const int i0 = blockIdx.y * 128;
    const int j0 = blockIdx.z * JW;

    __shared__ float znT[JW][68];    // [j][k_local]: broadcast rows
    __shared__ float ptT[JW][132];   // [j][i_local]: lane pair -> ds_read_b64

    const int tid = threadIdx.x;
    {   // stage Zn^T on the fly: 64 rows x 16 j (threads split j in halves)
        const int row = tid & 63;
        const int jh  = (tid >> 6) * 8;
        const size_t base = (size_t)(k0 + row) * OD + j0 + jh;
        float4 a0 = *(const float4*)(Zp + base);
        float4 a1 = *(const float4*)(Zp + base + 4);
        float4 b0 = *(const float4*)(Zp + (size_t)TOT * OD + base);
        float4 b1 = *(const float4*)(Zp + (size_t)TOT * OD + base + 4);
        const float m  = muv[k0 + row];
        const float iv = inv[k0 + row];
        float4 g0 = *(const float4*)(gamma + j0 + jh);
        float4 g1 = *(const float4*)(gamma + j0 + jh + 4);
        float4 e0 = *(const float4*)(beta + j0 + jh);
        float4 e1 = *(const float4*)(beta + j0 + jh + 4);
        znT[jh + 0][row] = (a0.x + b0.x - m) * iv * g0.x + e0.x;
        znT[jh + 1][row] = (a0.y + b0.y - m) * iv * g0.y + e0.y;
        znT[jh + 2][row] = (a0.z + b0.z - m) * iv * g0.z + e0.z;
        znT[jh + 3][row] = (a0.w + b0.w - m) * iv * g0.w + e0.w;
        znT[jh + 4][row] = (a1.x + b1.x - m) * iv * g1.x + e1.x;
        znT[jh + 5][row] = (a1.y + b1.y - m) * iv * g1.y + e1.y;
        znT[jh + 6][row] = (a1.z + b1.z - m) * iv * g1.z + e1.z;
        znT[jh + 7][row] = (a1.w + b1.w - m) * iv * g1.w + e1.w;
        // stage P^T: 128 i rows x 16 j
        const float* pr = P + (size_t)(i0 + tid) * OD + j0;
        float4 p0 = *(const float4*)(pr);
        float4 p1 = *(const float4*)(pr + 4);
        float4 p2 = *(const float4*)(pr + 8);
        float4 p3 = *(const float4*)(pr + 12);
        ptT[ 0][tid] = p0.x; ptT[ 1][tid] = p0.y; ptT[ 2][tid] = p0.z; ptT[ 3][tid] = p0.w;
        ptT[ 4][tid] = p1.x; ptT[ 5][tid] = p1.y; ptT[ 6][tid] = p1.z; ptT[ 7][tid] = p1.w;
        ptT[ 8][tid] = p2.x; ptT[ 9][tid] = p2.y; ptT[10][tid] = p2.z; ptT[11][tid] = p2.w;
        ptT[12][tid] = p3.x; ptT[13][tid] = p3.y; ptT[14][tid] = p3.z; ptT[15][tid] = p3.w;
    }
    __syncthreads();

    const int kg = tid >> 6;              // wave = k-half
    const int l  = tid & 63;
    const int il = 2 * l;                 // local i pair
    const float kbase = (float)(k0 + kg * 32);
    const float pbA   = (float)((i0 + il) * OD + j0 + 2);     // exact (< 2^24)

    f32x2 accA[16], accB[16];
#pragma unroll
    for (int m = 0; m < 16; ++m) { accA[m] = (f32x2){0.f, 0.f}; accB[m] = (f32x2){0.f, 0.f}; }

    const float* zrow = &znT[0][kg * 32];

    for (int j = 0; j < JW; ++j) {
        f32x2 wp = *(const f32x2*)&ptT[j][il];    // {wA, wB} one b64
        const float pA  = pbA + (float)j;
        const float ipA = __builtin_amdgcn_rcpf(pA);
        const float aA  = __builtin_amdgcn_fractf(kbase * ipA);
        const float c0A = __builtin_amdgcn_cosf(aA);
        const float s0A = __builtin_amdgcn_sinf(aA);
        const float cdA = __builtin_amdgcn_cosf(ipA);
        const float sdA = __builtin_amdgcn_sinf(ipA);
        const float c1A = c0A * cdA - s0A * sdA;
        const float s1A = s0A * cdA + c0A * sdA;
        const float c2A = c1A * cdA - s1A * sdA;
        const float c3A = c2A * cdA - (s1A * cdA + c1A * sdA) * sdA;
        const float r2A = 2.f * (1.f - 2.f * sdA * sdA);
        f32x2 DA_p = {wp.x * c0A, wp.x * c1A};
        f32x2 DA_c = {wp.x * c2A, wp.x * c3A};
        const f32x2 RA = {r2A, r2A};
        const float pB  = pA + 256.f;
        const float ipB = __builtin_amdgcn_rcpf(pB);
        const float aB  = __builtin_amdgcn_fractf(kbase * ipB);
        const float c0B = __builtin_amdgcn_cosf(aB);
        const float s0B = __builtin_amdgcn_sinf(aB);
        const float cdB = __builtin_amdgcn_cosf(ipB);
        const float sdB = __builtin_amdgcn_sinf(ipB);
        const float c1B = c0B * cdB - s0B * sdB;
        const float s1B = s0B * cdB + c0B * sdB;
        const float c2B = c1B * cdB - s1B * sdB;
        const float c3B = c2B * cdB - (s1B * cdB + c1B * sdB) * sdB;
        const float r2B = 2.f * (1.f - 2.f * sdB * sdB);
        f32x2 DB_p = {wp.y * c0B, wp.y * c1B};
        f32x2 DB_c = {wp.y * c2B, wp.y * c3B};
        const f32x2 RB = {r2B, r2B};

        const float* zc = zrow + (size_t)j * 68;
#pragma unroll
        for (int m = 0; m < 8; ++m) {     // 8 x float4 = 32 k = 16 pairs
            float4 z4 = *(const float4*)(zc + 4 * m);
            f32x2 zlo = {z4.x, z4.y};
            f32x2 zhi = {z4.z, z4.w};
            accA[2 * m    ] += zlo * DA_p;
            accB[2 * m    ] += zlo * DB_p;
            f32x2 tA = RA * DA_c - DA_p;  DA_p = DA_c;  DA_c = tA;
            f32x2 tB = RB * DB_c - DB_p;  DB_p = DB_c;  DB_c = tB;
            accA[2 * m + 1] += zhi * DA_p;
            accB[2 * m + 1] += zhi * DB_p;
            tA = RA * DA_c - DA_p;  DA_p = DA_c;  DA_c = tA;
            tB = RB * DB_c - DB_p;  DB_p = DB_c;  DB_c = tB;
        }
    }

    short* Tpl = Tp + (size_t)blockIdx.z * (TOT * OD);
    const int ia = i0 + il;
    const int kb = k0 + kg * 32;
#pragma unroll
    for (int m = 0; m < 16; ++m) {
        *(uint*)(Tpl + (size_t)(kb + 2 * m    ) * OD + ia) = pack2(accA[m].x, accB[m].x);
        *(uint*)(Tpl + (size_t)(kb + 2 * m + 1) * OD + ia) = pack2(accA[m].y, accB[m].y);
    }

    // ---- last-of-16 epilogue: W-tile = Zp0+Zp1+sum(Tp) (f32, row-major) ----
    __threadfence();
    __syncthreads();
    __shared__ int lastf;
    if (tid == 0)
        lastf = (atomicAdd(&cnt[blockIdx.x * 2 + blockIdx.y], 1) == JSPL - 1);
    __syncthreads();
    if (!lastf) return;

#pragma unroll
    for (int e = 0; e < 32; ++e) {        // 64 rows x 128 cols = 4096 pairs / 128 thr
        const int lin = e * 128 + tid;    // pair index
        const int r   = lin >> 6;         // 0..63
        const int c2  = (lin & 63) * 2;   // 0..126
        const size_t addr = (size_t)(k0 + r) * OD + i0 + c2;
        float wx = Zp[addr]     + Zp[(size_t)TOT * OD + addr];
        float wy = Zp[addr + 1] + Zp[(size_t)TOT * OD + addr + 1];
#pragma unroll
        for (int p = 0; p < JSPL; ++p) {
            uint t = *(const uint*)(Tp + (size_t)p * (TOT * OD) + addr);
            wx += bflo(t); wy += bfhi(t);
        }
        *(f32x2*)(W + addr) = (f32x2){wx, wy};
    }
}

// ============ K3f: Op[ksp][b] = L^T * W_b^T, A/B transposed+cvt inline; ============
// last-of-4 epilogue sums Op planes -> out (+ out_seq scalar).
__global__ __launch_bounds__(256, 4) void k3_mfma(
    const float* __restrict__ L, const float* __restrict__ W,
    float* __restrict__ Op, float* __restrict__ out, int out_size,
    int* __restrict__ cnt)
{
    const int b   = blockIdx.z & 1;
    const int ksp = blockIdx.z >> 1;
    const int r0  = blockIdx.x * 64;     // t range
    const int c0  = blockIdx.y * 64;     // o range
    const int k0  = ksp * (SEQL / K3SPL);

    __shared__ short Al[64][40];
    __shared__ short Bl[64][40];
    const int tid = threadIdx.x;
    const int w   = tid >> 6;
    const int wm  = w >> 1, wn = w & 1;
    const int l   = tid & 63;
    const int lr  = l & 15, lg = l >> 4;
    const int sq  = tid >> 3;            // 0..31 (s/k row)
    const int tc  = (tid & 7) * 8;       // 0..56 (t/o col group)

    f32x4 acc[2][2] = {{{0.f,0.f,0.f,0.f},{0.f,0.f,0.f,0.f}},
                       {{0.f,0.f,0.f,0.f},{0.f,0.f,0.f,0.f}}};

    const float* Wb = W + (size_t)b * SEQL * OD;

    for (int ks = 0; ks < (SEQL / K3SPL) / 32; ++ks) {
        const int kb = k0 + ks * 32;
        __syncthreads();
        {   // A[t][s] = L[kb+sq][r0+tc..+8]  (transpose + cvt)
            const float* ar = L + (size_t)(kb + sq) * TQ + r0 + tc;
            float4 a0 = *(const float4*)ar, a1 = *(const float4*)(ar + 4);
            Al[tc + 0][sq] = f2bf(a0.x); Al[tc + 1][sq] = f2bf(a0.y);
            Al[tc + 2][sq] = f2bf(a0.z); Al[tc + 3][sq] = f2bf(a0.w);
            Al[tc + 4][sq] = f2bf(a1.x); Al[tc + 5][sq] = f2bf(a1.y);
            Al[tc + 6][sq] = f2bf(a1.z); Al[tc + 7][sq] = f2bf(a1.w);
            // B[o][s] = W[b, kb+sq][c0+tc..+8]  (transpose + cvt)
            const float* br = Wb + (size_t)(kb + sq) * OD + c0 + tc;
            float4 b0 = *(const float4*)br, b1 = *(const float4*)(br + 4);
            Bl[tc + 0][sq] = f2bf(b0.x); Bl[tc + 1][sq] = f2bf(b0.y);
            Bl[tc + 2][sq] = f2bf(b0.z); Bl[tc + 3][sq] = f2bf(b0.w);
            Bl[tc + 4][sq] = f2bf(b1.x); Bl[tc + 5][sq] = f2bf(b1.y);
            Bl[tc + 6][sq] = f2bf(b1.z); Bl[tc + 7][sq] = f2bf(b1.w);
        }
        __syncthreads();
        bf16x8 a0 = *(const bf16x8*)&Al[wm * 32 +      lr][lg * 8];
        bf16x8 a1 = *(const bf16x8*)&Al[wm * 32 + 16 + lr][lg * 8];
        bf16x8 b0 = *(const bf16x8*)&Bl[wn * 32 +      lr][lg * 8];
        bf16x8 b1 = *(const bf16x8*)&Bl[wn * 32 + 16 + lr][lg * 8];
        acc[0][0] = __builtin_amdgcn_mfma_f32_16x16x32_bf16(a0, b0, acc[0][0], 0, 0, 0);
        acc[0][1] = __builtin_amdgcn_mfma_f32_16x16x32_bf16(a0, b1, acc[0][1], 0, 0, 0);
        acc[1][0] = __builtin_amdgcn_mfma_f32_16x16x32_bf16(a1, b0, acc[1][0], 0, 0, 0);
        acc[1][1] = __builtin_amdgcn_mfma_f32_16x16x32_bf16(a1, b1, acc[1][1], 0, 0, 0);
    }

    float* Cp = Op + (size_t)ksp * (NB * TQ * OD) + (size_t)b * TQ * OD;
#pragma unroll
    for (int sm = 0; sm < 2; ++sm)
#pragma unroll
    for (int sn = 0; sn < 2; ++sn)
#pragma unroll
    for (int q = 0; q < 4; ++q)
        Cp[(size_t)(r0 + wm * 32 + sm * 16 + 4 * lg + q) * OD
           + (c0 + wn * 32 + sn * 16 + lr)] = acc[sm][sn][q];

    // ---- last-of-4 epilogue: out-tile = sum of K3SPL Op planes ----
    __threadfence();
    __syncthreads();
    __shared__ int lastf;
    if (tid == 0)
        lastf = (atomicAdd(&cnt[(blockIdx.x * 4 + blockIdx.y) * 2 + b], 1) == K3SPL - 1);
    __syncthreads();
    if (!lastf) return;

#pragma unroll
    for (int e = 0; e < 4; ++e) {         // 64x64 = 1024 float4s / 256 thr
        const int lin = e * 256 + tid;
        const int r   = lin >> 4;         // 0..63
        const int c4  = (lin & 15) * 4;   // 0..60
        const size_t addr = ((size_t)(b * TQ) + r0 + r) * OD + c0 + c4;
        float4 a = *(const float4*)(Op + addr);
#pragma unroll
        for (int p = 1; p < K3SPL; ++p) {
            float4 t = *(const float4*)(Op + (size_t)p * (NB * TQ * OD) + addr);
            a.x += t.x; a.y += t.y; a.z += t.z; a.w += t.w;
        }
        *(float4*)(out + addr) = a;
    }
    if (tid == 0 && blockIdx.x == 0 && blockIdx.y == 0 && b == 0
        && out_size > NB * TQ * OD)
        out[NB * TQ * OD] = (float)TQ;    // second output: out_seq = 512
}

extern "C" void kernel_launch(void* const* d_in, const int* in_sizes, int n_in,
                              void* d_out, int out_size, void* d_ws, size_t ws_size,
                              hipStream_t stream)
{
    const float* x  = (const float*)d_in[0];
    const float* M  = (const float*)d_in[1];
    const float* P  = (const float*)d_in[2];
    const float* L  = (const float*)d_in[3];
    const float* g  = (const float*)d_in[4];
    const float* be = (const float*)d_in[5];
    float* out = (float*)d_out;

    int*   cnt  = (int*)d_ws;                       // cnt1[32] | cnt2[64] | cnt3[64]
    int*   cnt1 = cnt;
    int*   cnt2 = cnt + 32;
    int*   cnt3 = cnt + 96;
    float* base = (float*)d_ws + 256;
    float* Zp  = base;                              // 2 * TOT*OD
    float* W   = Zp + 2 * (size_t)TOT * OD;         // TOT*OD
    float* Op  = W  + (size_t)TOT * OD;             // K3SPL * NB*TQ*OD
    float* muv = Op + (size_t)K3SPL * NB * TQ * OD; // TOT
    float* inv = muv + TOT;                         // TOT
    short* Tp  = (short*)(inv + TOT);               // JSPL * TOT*OD bf16

    hipMemsetAsync(cnt, 0, 160 * sizeof(int), stream);
    k1_mfma<<<dim3(TOT / 64, OD / 64, 2), 256, 0, stream>>>(x, M, Zp, muv, inv, cnt1);
    k2_t<<<dim3(TOT / 64, OD / 128, JSPL), 128, 0, stream>>>(Zp, muv, inv, g, be, P, Tp, W, cnt2);
    k3_mfma<<<dim3(TQ / 64, OD / 64, NB * K3SPL), 256, 0, stream>>>(L, W, Op, out, out_size, cnt3);
}

// Round 14
// 53.150 us; speedup vs baseline: 3.1758x; 3.1758x over previous
//
#include <hip/hip_runtime.h>
#include <hip/hip_bf16.h>

#define TOT     2048      // B*SEQ rows
#define INDIM   512
#define OD      256
#define SEQL    1024
#define TQ      512       // out_seq
#define NB      2
#define LN_EPS  1e-5f

#define JSPL    16        // k2 j-split (planes)
#define JW      (OD / JSPL)      // 16 j per k2 block

typedef __attribute__((ext_vector_type(8))) short bf16x8;
typedef __attribute__((ext_vector_type(4))) float f32x4;
typedef __attribute__((ext_vector_type(2))) float f32x2;

__device__ __forceinline__ short f2bf(float f) {
    __hip_bfloat16 h = __float2bfloat16(f);
    return *(short*)&h;
}
__device__ __forceinline__ uint pack2(float a, float b) {
    return (uint)(ushort)f2bf(a) | ((uint)(ushort)f2bf(b) << 16);
}

// ============ kcvt: xb = bf16(x); Mb = bf16(M); ALt = bf16(Linker^T) ============
__global__ __launch_bounds__(256) void kcvt(
    const float* __restrict__ x, const float* __restrict__ M,
    const float* __restrict__ L,
    short* __restrict__ xb, short* __restrict__ Mb, short* __restrict__ ALt,
    float* __restrict__ out, int out_size)
{
    const int bid = blockIdx.x;
    const int tid = threadIdx.x;
    if (bid == 0 && tid == 0 && out_size > NB * TQ * OD)
        out[NB * TQ * OD] = (float)TQ;      // second output: out_seq = 512
    if (bid < 1024) {                       // x: 2048*512 = 1M elems, 4/thread
        const int i = (bid * 256 + tid) * 4;
        float4 v = *(const float4*)(x + i);
        *(uint2*)(xb + i) = make_uint2(pack2(v.x, v.y), pack2(v.z, v.w));
    } else if (bid < 1152) {                // M: 256*512 = 128K elems
        const int i = ((bid - 1024) * 256 + tid) * 4;
        float4 v = *(const float4*)(M + i);
        *(uint2*)(Mb + i) = make_uint2(pack2(v.x, v.y), pack2(v.z, v.w));
    } else {                                // Linker transpose: 32x32 tiles
        __shared__ float tl[32][36];
        const int tt = bid - 1152;          // 512 tiles: 32 s-tiles x 16 t-tiles
        const int s0 = (tt >> 4) * 32;
        const int t0 = (tt & 15) * 32;
        const int r  = tid >> 3;
        const int c4 = (tid & 7) * 4;
        float4 v = *(const float4*)(L + (size_t)(s0 + r) * TQ + t0 + c4);
        tl[r][c4 + 0] = v.x; tl[r][c4 + 1] = v.y;
        tl[r][c4 + 2] = v.z; tl[r][c4 + 3] = v.w;
        __syncthreads();
        uint lo = pack2(tl[c4 + 0][r], tl[c4 + 1][r]);
        uint hi = pack2(tl[c4 + 2][r], tl[c4 + 3][r]);
        *(uint2*)(ALt + (size_t)(t0 + r) * SEQL + s0 + c4) = make_uint2(lo, hi);
    }
}

// ============ shared 64x64 MFMA tile: C = A[rows][k] * B[cols][k]^T ============
__device__ __forceinline__ void mfma_tile64(
    const short* __restrict__ A, int lda,
    const short* __restrict__ B, int ldb,
    float* __restrict__ C, int ldc,
    int r0, int c0, int k0, int nk)
{
    __shared__ short Al[64][40];   // pad to 40 bf16 (80 B rows, 16B-aligned)
    __shared__ short Bl[64][40];
    const int tid = threadIdx.x;
    const int w   = tid >> 6;
    const int wm  = w >> 1, wn = w & 1;
    const int l   = tid & 63;
    const int lr  = l & 15, lg = l >> 4;
    const int srow = tid >> 2, skg = (tid & 3) * 8;

    f32x4 acc[2][2] = {{{0.f,0.f,0.f,0.f},{0.f,0.f,0.f,0.f}},
                       {{0.f,0.f,0.f,0.f},{0.f,0.f,0.f,0.f}}};

    for (int ks = 0; ks < nk; ++ks) {
        const int kb = k0 + ks * 32;
        __syncthreads();
        *(bf16x8*)&Al[srow][skg] = *(const bf16x8*)(A + (size_t)(r0 + srow) * lda + kb + skg);
        *(bf16x8*)&Bl[srow][skg] = *(const bf16x8*)(B + (size_t)(c0 + srow) * ldb + kb + skg);
        __syncthreads();
        bf16x8 a0 = *(const bf16x8*)&Al[wm * 32 +      lr][lg * 8];
        bf16x8 a1 = *(const bf16x8*)&Al[wm * 32 + 16 + lr][lg * 8];
        bf16x8 b0 = *(const bf16x8*)&Bl[wn * 32 +      lr][lg * 8];
        bf16x8 b1 = *(const bf16x8*)&Bl[wn * 32 + 16 + lr][lg * 8];
        acc[0][0] = __builtin_amdgcn_mfma_f32_16x16x32_bf16(a0, b0, acc[0][0], 0, 0, 0);
        acc[0][1] = __builtin_amdgcn_mfma_f32_16x16x32_bf16(a0, b1, acc[0][1], 0, 0, 0);
        acc[1][0] = __builtin_amdgcn_mfma_f32_16x16x32_bf16(a1, b0, acc[1][0], 0, 0, 0);
        acc[1][1] = __builtin_amdgcn_mfma_f32_16x16x32_bf16(a1, b1, acc[1][1], 0, 0, 0);
    }
    // D: col = lane&15, row = 4*(lane>>4)+reg  [m89-verified]
#pragma unroll
    for (int sm = 0; sm < 2; ++sm)
#pragma unroll
    for (int sn = 0; sn < 2; ++sn)
#pragma unroll
    for (int q = 0; q < 4; ++q)
        C[(size_t)(r0 + wm * 32 + sm * 16 + 4 * lg + q) * ldc
          + (c0 + wn * 32 + sn * 16 + lr)] = acc[sm][sn][q];
}

// ============ K1: Zp[h] = xb * Mb^T (K-half h) ============
__global__ __launch_bounds__(256, 4) void k1_mfma(
    const short* __restrict__ xb, const short* __restrict__ Mb,
    float* __restrict__ Zp)
{
    mfma_tile64(xb, INDIM, Mb, INDIM,
                Zp + (size_t)blockIdx.z * TOT * OD, OD,
                blockIdx.x * 64, blockIdx.y * 64, blockIdx.z * 256, 8);
}

// ============ K1b: Z = Zp0+Zp1; Zn = LayerNorm(Z) ============
__global__ __launch_bounds__(256) void k1b_ln(
    const float* __restrict__ Zp,
    const float* __restrict__ gamma, const float* __restrict__ beta,
    float* __restrict__ Z, float* __restrict__ Zn)
{
    const int r0 = blockIdx.x * 8;
    const int c  = threadIdx.x;

    float acc[8];
#pragma unroll
    for (int r = 0; r < 8; ++r) {
        const size_t i = (size_t)(r0 + r) * OD + c;
        acc[r] = Zp[i] + Zp[(size_t)TOT * OD + i];
    }

    __shared__ float s1[8][4], s2[8][4];
    const int lane = c & 63;
    const int wid  = c >> 6;
#pragma unroll
    for (int r = 0; r < 8; ++r) {
        float s = acc[r], q = acc[r] * acc[r];
#pragma unroll
        for (int off = 32; off > 0; off >>= 1) {
            s += __shfl_xor(s, off, 64);
            q += __shfl_xor(q, off, 64);
        }
        if (lane == 0) { s1[r][wid] = s; s2[r][wid] = q; }
    }
    __syncthreads();
#pragma unroll
    for (int r = 0; r < 8; ++r) {
        float s  = s1[r][0] + s1[r][1] + s1[r][2] + s1[r][3];
        float q  = s2[r][0] + s2[r][1] + s2[r][2] + s2[r][3];
        float mu = s * (1.f / OD);
        float var = q * (1.f / OD) - mu * mu;
        float inv = rsqrtf(var + LN_EPS);
        float z  = acc[r];
        float zn = (z - mu) * inv * gamma[c] + beta[c];
        Z [(size_t)(r0 + r) * OD + c] = z;
        Zn[(size_t)(r0 + r) * OD + c] = zn;
    }
}

// ============ K2 v3: T[k,i] = sum_j Zn[k,j]*P[i,j]*cos(2*pi*k/(i*256+j+2)) ============
// d-recurrence: d_k = P[i,j]*cos(2pi k/p) satisfies d_{k+2} = 2cos(2d)*d_k - d_{k-2};
// P folded into initial conditions -> inner loop = 1 acc-fma + 1 advance-fma per pair.
// Lane owns 32 k (kg = wave) x 2 adjacent i; block 128 thr; tile 64k x 128i x 16j.
__global__ __launch_bounds__(128) void k2_t(
    const float* __restrict__ Zn, const float* __restrict__ P,
    short* __restrict__ Tp)
{
    const int k0 = blockIdx.x * 64;
    const int i0 = blockIdx.y * 128;
    const int j0 = blockIdx.z * JW;

    __shared__ float znT[JW][68];    // [j][k_local]: broadcast rows
    __shared__ float ptT[JW][132];   // [j][i_local]: lane pair -> ds_read_b64

    const int tid = threadIdx.x;
    {   // stage Zn^T: 64 rows x 16 j, threads split j in halves
        const int row = tid & 63;
        const int jh  = (tid >> 6) * 8;
        const float* zr = Zn + (size_t)(k0 + row) * OD + j0 + jh;
        float4 v0 = *(const float4*)(zr);
        float4 v1 = *(const float4*)(zr + 4);
        znT[jh + 0][row] = v0.x; znT[jh + 1][row] = v0.y;
        znT[jh + 2][row] = v0.z; znT[jh + 3][row] = v0.w;
        znT[jh + 4][row] = v1.x; znT[jh + 5][row] = v1.y;
        znT[jh + 6][row] = v1.z; znT[jh + 7][row] = v1.w;
        // stage P^T: 128 i rows x 16 j
        const float* pr = P + (size_t)(i0 + tid) * OD + j0;
        float4 p0 = *(const float4*)(pr);
        float4 p1 = *(const float4*)(pr + 4);
        float4 p2 = *(const float4*)(pr + 8);
        float4 p3 = *(const float4*)(pr + 12);
        ptT[ 0][tid] = p0.x; ptT[ 1][tid] = p0.y; ptT[ 2][tid] = p0.z; ptT[ 3][tid] = p0.w;
        ptT[ 4][tid] = p1.x; ptT[ 5][tid] = p1.y; ptT[ 6][tid] = p1.z; ptT[ 7][tid] = p1.w;
        ptT[ 8][tid] = p2.x; ptT[ 9][tid] = p2.y; ptT[10][tid] = p2.z; ptT[11][tid] = p2.w;
        ptT[12][tid] = p3.x; ptT[13][tid] = p3.y; ptT[14][tid] = p3.z; ptT[15][tid] = p3.w;
    }
    __syncthreads();

    const int kg = tid >> 6;              // wave = k-half
    const int l  = tid & 63;
    const int il = 2 * l;                 // local i pair
    const float kbase = (float)(k0 + kg * 32);
    const float pbA   = (float)((i0 + il) * OD + j0 + 2);     // exact (< 2^24)

    f32x2 accA[16], accB[16];
#pragma unroll
    for (int m = 0; m < 16; ++m) { accA[m] = (f32x2){0.f, 0.f}; accB[m] = (f32x2){0.f, 0.f}; }

    const float* zrow = &znT[0][kg * 32];

    for (int j = 0; j < JW; ++j) {
        f32x2 wp = *(const f32x2*)&ptT[j][il];    // {wA, wB} one b64
        const float pA  = pbA + (float)j;
        const float ipA = __builtin_amdgcn_rcpf(pA);
        const float aA  = __builtin_amdgcn_fractf(kbase * ipA);
        const float c0A = __builtin_amdgcn_cosf(aA);
        const float s0A = __builtin_amdgcn_sinf(aA);
        const float cdA = __builtin_amdgcn_cosf(ipA);
        const float sdA = __builtin_amdgcn_sinf(ipA);
        const float c1A = c0A * cdA - s0A * sdA;
        const float s1A = s0A * cdA + c0A * sdA;
        const float c2A = c1A * cdA - s1A * sdA;
        const float c3A = c2A * cdA - (s1A * cdA + c1A * sdA) * sdA;
        const float r2A = 2.f * (1.f - 2.f * sdA * sdA);
        f32x2 DA_p = {wp.x * c0A, wp.x * c1A};
        f32x2 DA_c = {wp.x * c2A, wp.x * c3A};
        const f32x2 RA = {r2A, r2A};
        const float pB  = pA + 256.f;
        const float ipB = __builtin_amdgcn_rcpf(pB);
        const float aB  = __builtin_amdgcn_fractf(kbase * ipB);
        const float c0B = __builtin_amdgcn_cosf(aB);
        const float s0B = __builtin_amdgcn_sinf(aB);
        const float cdB = __builtin_amdgcn_cosf(ipB);
        const float sdB = __builtin_amdgcn_sinf(ipB);
        const float c1B = c0B * cdB - s0B * sdB;
        const float s1B = s0B * cdB + c0B * sdB;
        const float c2B = c1B * cdB - s1B * sdB;
        const float c3B = c2B * cdB - (s1B * cdB + c1B * sdB) * sdB;
        const float r2B = 2.f * (1.f - 2.f * sdB * sdB);
        f32x2 DB_p = {wp.y * c0B, wp.y * c1B};
        f32x2 DB_c = {wp.y * c2B, wp.y * c3B};
        const f32x2 RB = {r2B, r2B};

        const float* zc = zrow + (size_t)j * 68;
#pragma unroll
        for (int m = 0; m < 8; ++m) {     // 8 x float4 = 32 k = 16 pairs
            float4 z4 = *(const float4*)(zc + 4 * m);
            f32x2 zlo = {z4.x, z4.y};
            f32x2 zhi = {z4.z, z4.w};
            accA[2 * m    ] += zlo * DA_p;
            accB[2 * m    ] += zlo * DB_p;
            f32x2 tA = RA * DA_c - DA_p;  DA_p = DA_c;  DA_c = tA;
            f32x2 tB = RB * DB_c - DB_p;  DB_p = DB_c;  DB_c = tB;
            accA[2 * m + 1] += zhi * DA_p;
            accB[2 * m + 1] += zhi * DB_p;
            tA = RA * DA_c - DA_p;  DA_p = DA_c;  DA_c = tA;
            tB = RB * DB_c - DB_p;  DB_p = DB_c;  DB_c = tB;
        }
    }

    short* Tpl = Tp + (size_t)blockIdx.z * (TOT * OD);
    const int ia = i0 + il;
    const int kb = k0 + kg * 32;
#pragma unroll
    for (int m = 0; m < 16; ++m) {
        *(uint*)(Tpl + (size_t)(kb + 2 * m    ) * OD + ia) = pack2(accA[m].x, accB[m].x);
        *(uint*)(Tpl + (size_t)(kb + 2 * m + 1) * OD + ia) = pack2(accA[m].y, accB[m].y);
    }
}

// ============ K2b: Wt[b][o][s] = bf16(Z + sum Tp) transposed ============
__global__ __launch_bounds__(256) void k2b_w(
    const float* __restrict__ Z, const short* __restrict__ Tp,
    short* __restrict__ Wt)
{
    __shared__ float tl[32][36];
    const int kt0 = blockIdx.x * 32;    // global k = b*1024+s
    const int o0  = blockIdx.y * 32;
    const int tid = threadIdx.x;
    const int r   = tid >> 3;           // 0..31 (kt row)
    const int c4  = (tid & 7) * 4;      // 0..28 (o col)

    const size_t idx = (size_t)(kt0 + r) * OD + o0 + c4;
    float4 z = *(const float4*)(Z + idx);
#pragma unroll
    for (int p = 0; p < JSPL; ++p) {
        uint2 t = *(const uint2*)(Tp + (size_t)p * (TOT * OD) + idx);
        z.x += __uint_as_float(t.x << 16);
        z.y += __uint_as_float(t.x & 0xFFFF0000u);
        z.z += __uint_as_float(t.y << 16);
        z.w += __uint_as_float(t.y & 0xFFFF0000u);
    }
    *(float4*)&tl[r][c4] = z;
    __syncthreads();

    const int ol = tid >> 3;            // 0..31 (o row out)
    const int sc = (tid & 7) * 4;       // 0..28 (s col out)
    const int b  = kt0 >> 10;
    const int sb = kt0 & 1023;
    uint lo = pack2(tl[sc + 0][ol], tl[sc + 1][ol]);
    uint hi = pack2(tl[sc + 2][ol], tl[sc + 3][ol]);
    *(uint2*)(Wt + ((size_t)b * OD + o0 + ol) * SEQL + sb + sc) = make_uint2(lo, hi);
}

// ============ K3: out[b] = ALt * Wt_b^T, full K=1024 per block ============
// Grid (TQ/64, OD/64, NB) = 64 blocks; writes out directly (no Op planes, no k4).
__global__ __launch_bounds__(256, 4) void k3_mfma(
    const short* __restrict__ ALt, const short* __restrict__ Wt,
    float* __restrict__ out)
{
    const int b = blockIdx.z;
    mfma_tile64(ALt, SEQL, Wt + (size_t)b * OD * SEQL, SEQL,
                out + (size_t)b * TQ * OD, OD,
                blockIdx.x * 64, blockIdx.y * 64, 0, SEQL / 32);
}

extern "C" void kernel_launch(void* const* d_in, const int* in_sizes, int n_in,
                              void* d_out, int out_size, void* d_ws, size_t ws_size,
                              hipStream_t stream)
{
    const float* x  = (const float*)d_in[0];
    const float* M  = (const float*)d_in[1];
    const float* P  = (const float*)d_in[2];
    const float* L  = (const float*)d_in[3];
    const float* g  = (const float*)d_in[4];
    const float* be = (const float*)d_in[5];
    float* out = (float*)d_out;

    float* ws_f = (float*)d_ws;
    float* Zp = ws_f;                               // 2 * TOT*OD f32
    float* Z  = Zp + 2 * (size_t)TOT * OD;          // TOT*OD f32
    float* Zn = Z  + (size_t)TOT * OD;              // TOT*OD f32
    short* xb  = (short*)(Zn + (size_t)TOT * OD);
    short* Mb  = xb  + (size_t)TOT * INDIM;
    short* ALt = Mb  + (size_t)OD * INDIM;
    short* Wt  = ALt + (size_t)TQ * SEQL;
    short* Tp  = Wt  + (size_t)NB * OD * SEQL;      // JSPL * TOT*OD bf16

    kcvt<<<1664, 256, 0, stream>>>(x, M, L, xb, Mb, ALt, out, out_size);
    k1_mfma<<<dim3(TOT / 64, OD / 64, 2), 256, 0, stream>>>(xb, Mb, Zp);
    k1b_ln<<<TOT / 8, 256, 0, stream>>>(Zp, g, be, Z, Zn);
    k2_t<<<dim3(TOT / 64, OD / 128, JSPL), 128, 0, stream>>>(Zn, P, Tp);
    k2b_w<<<dim3(TOT / 32, OD / 32), 256, 0, stream>>>(Z, Tp, Wt);
    k3_mfma<<<dim3(TQ / 64, OD / 64, NB), 256, 0, stream>>>(ALt, Wt, out);
}

// Round 15
// 45.415 us; speedup vs baseline: 3.7168x; 1.1703x over previous
//
#include <hip/hip_runtime.h>
#include <hip/hip_bf16.h>

#define TOT     2048      // B*SEQ rows
#define INDIM   512
#define OD      256
#define SEQL    1024
#define TQ      512       // out_seq
#define NB      2
#define LN_EPS  1e-5f

#define JSPL    16        // k2 j-split (planes)
#define JW      (OD / JSPL)      // 16 j per k2 block
#define K3SPL   8         // k3 K-split

typedef __attribute__((ext_vector_type(8))) short bf16x8;
typedef __attribute__((ext_vector_type(4))) float f32x4;
typedef __attribute__((ext_vector_type(2))) float f32x2;

__device__ __forceinline__ short f2bf(float f) {
    __hip_bfloat16 h = __float2bfloat16(f);
    return *(short*)&h;
}
__device__ __forceinline__ uint pack2(float a, float b) {
    return (uint)(ushort)f2bf(a) | ((uint)(ushort)f2bf(b) << 16);
}

// ============ shared 64x64 MFMA tile: C = A[rows][k] * B[cols][k]^T ============
// CVT: operands are f32 in global, converted to bf16 during LDS staging.
template<bool CVT>
__device__ __forceinline__ void mfma_tile64(
    const void* __restrict__ Av, int lda,
    const void* __restrict__ Bv, int ldb,
    float* __restrict__ C, int ldc,
    int r0, int c0, int k0, int nk)
{
    __shared__ short Al[64][40];   // pad to 40 bf16 (80 B rows, 16B-aligned)
    __shared__ short Bl[64][40];
    const int tid = threadIdx.x;
    const int w   = tid >> 6;
    const int wm  = w >> 1, wn = w & 1;
    const int l   = tid & 63;
    const int lr  = l & 15, lg = l >> 4;
    const int srow = tid >> 2, skg = (tid & 3) * 8;

    f32x4 acc[2][2] = {{{0.f,0.f,0.f,0.f},{0.f,0.f,0.f,0.f}},
                       {{0.f,0.f,0.f,0.f},{0.f,0.f,0.f,0.f}}};

    for (int ks = 0; ks < nk; ++ks) {
        const int kb = k0 + ks * 32;
        __syncthreads();
        if (CVT) {
            const float* Af = (const float*)Av;
            const float* Bf = (const float*)Bv;
            const float* ar = Af + (size_t)(r0 + srow) * lda + kb + skg;
            float4 a0 = *(const float4*)ar, a1 = *(const float4*)(ar + 4);
            *(uint4*)&Al[srow][skg] = make_uint4(pack2(a0.x, a0.y), pack2(a0.z, a0.w),
                                                 pack2(a1.x, a1.y), pack2(a1.z, a1.w));
            const float* br = Bf + (size_t)(c0 + srow) * ldb + kb + skg;
            float4 b0 = *(const float4*)br, b1 = *(const float4*)(br + 4);
            *(uint4*)&Bl[srow][skg] = make_uint4(pack2(b0.x, b0.y), pack2(b0.z, b0.w),
                                                 pack2(b1.x, b1.y), pack2(b1.z, b1.w));
        } else {
            const short* As = (const short*)Av;
            const short* Bs = (const short*)Bv;
            *(bf16x8*)&Al[srow][skg] = *(const bf16x8*)(As + (size_t)(r0 + srow) * lda + kb + skg);
            *(bf16x8*)&Bl[srow][skg] = *(const bf16x8*)(Bs + (size_t)(c0 + srow) * ldb + kb + skg);
        }
        __syncthreads();
        bf16x8 a0 = *(const bf16x8*)&Al[wm * 32 +      lr][lg * 8];
        bf16x8 a1 = *(const bf16x8*)&Al[wm * 32 + 16 + lr][lg * 8];
        bf16x8 b0 = *(const bf16x8*)&Bl[wn * 32 +      lr][lg * 8];
        bf16x8 b1 = *(const bf16x8*)&Bl[wn * 32 + 16 + lr][lg * 8];
        acc[0][0] = __builtin_amdgcn_mfma_f32_16x16x32_bf16(a0, b0, acc[0][0], 0, 0, 0);
        acc[0][1] = __builtin_amdgcn_mfma_f32_16x16x32_bf16(a0, b1, acc[0][1], 0, 0, 0);
        acc[1][0] = __builtin_amdgcn_mfma_f32_16x16x32_bf16(a1, b0, acc[1][0], 0, 0, 0);
        acc[1][1] = __builtin_amdgcn_mfma_f32_16x16x32_bf16(a1, b1, acc[1][1], 0, 0, 0);
    }
    // D: col = lane&15, row = 4*(lane>>4)+reg  [m89-verified]
#pragma unroll
    for (int sm = 0; sm < 2; ++sm)
#pragma unroll
    for (int sn = 0; sn < 2; ++sn)
#pragma unroll
    for (int q = 0; q < 4; ++q)
        C[(size_t)(r0 + wm * 32 + sm * 16 + 4 * lg + q) * ldc
          + (c0 + wn * 32 + sn * 16 + lr)] = acc[sm][sn][q];
}

// ============ K1: Zp[h] = bf16(x) * bf16(M)^T (K-half h), cvt inline ============
__global__ __launch_bounds__(256, 4) void k1_mfma(
    const float* __restrict__ x, const float* __restrict__ M,
    float* __restrict__ Zp)
{
    mfma_tile64<true>(x, INDIM, M, INDIM,
                      Zp + (size_t)blockIdx.z * TOT * OD, OD,
                      blockIdx.x * 64, blockIdx.y * 64, blockIdx.z * 256, 8);
}

// ============ K1b: blocks 0..255: Z = Zp0+Zp1, Zn = LayerNorm(Z);
//                  blocks 256..767: ALt = bf16(Linker^T) (independent work) ====
__global__ __launch_bounds__(256) void k1b_ln(
    const float* __restrict__ Zp,
    const float* __restrict__ gamma, const float* __restrict__ beta,
    float* __restrict__ Z, float* __restrict__ Zn,
    const float* __restrict__ L, short* __restrict__ ALt)
{
    const int tid = threadIdx.x;
    if (blockIdx.x >= 256) {
        // ---- ALt transpose tile (needs nothing from k1) ----
        __shared__ float tl[32][36];
        const int tt = blockIdx.x - 256;    // 512 tiles: 32 s-tiles x 16 t-tiles
        const int s0 = (tt >> 4) * 32;
        const int t0 = (tt & 15) * 32;
        const int r  = tid >> 3;
        const int c4 = (tid & 7) * 4;
        float4 v = *(const float4*)(L + (size_t)(s0 + r) * TQ + t0 + c4);
        tl[r][c4 + 0] = v.x; tl[r][c4 + 1] = v.y;
        tl[r][c4 + 2] = v.z; tl[r][c4 + 3] = v.w;
        __syncthreads();
        uint lo = pack2(tl[c4 + 0][r], tl[c4 + 1][r]);
        uint hi = pack2(tl[c4 + 2][r], tl[c4 + 3][r]);
        *(uint2*)(ALt + (size_t)(t0 + r) * SEQL + s0 + c4) = make_uint2(lo, hi);
        return;
    }

    const int r0 = blockIdx.x * 8;
    const int c  = tid;

    float acc[8];
#pragma unroll
    for (int r = 0; r < 8; ++r) {
        const size_t i = (size_t)(r0 + r) * OD + c;
        acc[r] = Zp[i] + Zp[(size_t)TOT * OD + i];
    }

    __shared__ float s1[8][4], s2[8][4];
    const int lane = c & 63;
    const int wid  = c >> 6;
#pragma unroll
    for (int r = 0; r < 8; ++r) {
        float s = acc[r], q = acc[r] * acc[r];
#pragma unroll
        for (int off = 32; off > 0; off >>= 1) {
            s += __shfl_xor(s, off, 64);
            q += __shfl_xor(q, off, 64);
        }
        if (lane == 0) { s1[r][wid] = s; s2[r][wid] = q; }
    }
    __syncthreads();
#pragma unroll
    for (int r = 0; r < 8; ++r) {
        float s  = s1[r][0] + s1[r][1] + s1[r][2] + s1[r][3];
        float q  = s2[r][0] + s2[r][1] + s2[r][2] + s2[r][3];
        float mu = s * (1.f / OD);
        float var = q * (1.f / OD) - mu * mu;
        float inv = rsqrtf(var + LN_EPS);
        float z  = acc[r];
        float zn = (z - mu) * inv * gamma[c] + beta[c];
        Z [(size_t)(r0 + r) * OD + c] = z;
        Zn[(size_t)(r0 + r) * OD + c] = zn;
    }
}

// ============ K2 v3: T[k,i] = sum_j Zn[k,j]*P[i,j]*cos(2*pi*k/(i*256+j+2)) ============
// d-recurrence: d_k = P[i,j]*cos(2pi k/p) satisfies d_{k+2} = 2cos(2d)*d_k - d_{k-2};
// P folded into initial conditions -> inner loop = 1 acc-fma + 1 advance-fma per pair.
// Lane owns 32 k (kg = wave) x 2 adjacent i; block 128 thr; tile 64k x 128i x 16j.
__global__ __launch_bounds__(128) void k2_t(
    const float* __restrict__ Zn, const float* __restrict__ P,
    short* __restrict__ Tp)
{
    const int k0 = blockIdx.x * 64;
    const int i0 = blockIdx.y * 128;
    const int j0 = blockIdx.z * JW;

    __shared__ float znT[JW][68];    // [j][k_local]: broadcast rows
    __shared__ float ptT[JW][132];   // [j][i_local]: lane pair -> ds_read_b64

    const int tid = threadIdx.x;
    {   // stage Zn^T: 64 rows x 16 j, threads split j in halves
        const int row = tid & 63;
        const int jh  = (tid >> 6) * 8;
        const float* zr = Zn + (size_t)(k0 + row) * OD + j0 + jh;
        float4 v0 = *(const float4*)(zr);
        float4 v1 = *(const float4*)(zr + 4);
        znT[jh + 0][row] = v0.x; znT[jh + 1][row] = v0.y;
        znT[jh + 2][row] = v0.z; znT[jh + 3][row] = v0.w;
        znT[jh + 4][row] = v1.x; znT[jh + 5][row] = v1.y;
        znT[jh + 6][row] = v1.z; znT[jh + 7][row] = v1.w;
        // stage P^T: 128 i rows x 16 j
        const float* pr = P + (size_t)(i0 + tid) * OD + j0;
        float4 p0 = *(const float4*)(pr);
        float4 p1 = *(const float4*)(pr + 4);
        float4 p2 = *(const float4*)(pr + 8);
        float4 p3 = *(const float4*)(pr + 12);
        ptT[ 0][tid] = p0.x; ptT[ 1][tid] = p0.y; ptT[ 2][tid] = p0.z; ptT[ 3][tid] = p0.w;
        ptT[ 4][tid] = p1.x; ptT[ 5][tid] = p1.y; ptT[ 6][tid] = p1.z; ptT[ 7][tid] = p1.w;
        ptT[ 8][tid] = p2.x; ptT[ 9][tid] = p2.y; ptT[10][tid] = p2.z; ptT[11][tid] = p2.w;
        ptT[12][tid] = p3.x; ptT[13][tid] = p3.y; ptT[14][tid] = p3.z; ptT[15][tid] = p3.w;
    }
    __syncthreads();

    const int kg = tid >> 6;              // wave = k-half
    const int l  = tid & 63;
    const int il = 2 * l;                 // local i pair
    const float kbase = (float)(k0 + kg * 32);
    const float pbA   = (float)((i0 + il) * OD + j0 + 2);     // exact (< 2^24)

    f32x2 accA[16], accB[16];
#pragma unroll
    for (int m = 0; m < 16; ++m) { accA[m] = (f32x2){0.f, 0.f}; accB[m] = (f32x2){0.f, 0.f}; }

    const float* zrow = &znT[0][kg * 32];

    for (int j = 0; j < JW; ++j) {
        f32x2 wp = *(const f32x2*)&ptT[j][il];    // {wA, wB} one b64
        const float pA  = pbA + (float)j;
        const float ipA = __builtin_amdgcn_rcpf(pA);
        const float aA  = __builtin_amdgcn_fractf(kbase * ipA);
        const float c0A = __builtin_amdgcn_cosf(aA);
        const float s0A = __builtin_amdgcn_sinf(aA);
        const float cdA = __builtin_amdgcn_cosf(ipA);
        const float sdA = __builtin_amdgcn_sinf(ipA);
        const float c1A = c0A * cdA - s0A * sdA;
        const float s1A = s0A * cdA + c0A * sdA;
        const float c2A = c1A * cdA - s1A * sdA;
        const float c3A = c2A * cdA - (s1A * cdA + c1A * sdA) * sdA;
        const float r2A = 2.f * (1.f - 2.f * sdA * sdA);
        f32x2 DA_p = {wp.x * c0A, wp.x * c1A};
        f32x2 DA_c = {wp.x * c2A, wp.x * c3A};
        const f32x2 RA = {r2A, r2A};
        const float pB  = pA + 256.f;
        const float ipB = __builtin_amdgcn_rcpf(pB);
        const float aB  = __builtin_amdgcn_fractf(kbase * ipB);
        const float c0B = __builtin_amdgcn_cosf(aB);
        const float s0B = __builtin_amdgcn_sinf(aB);
        const float cdB = __builtin_amdgcn_cosf(ipB);
        const float sdB = __builtin_amdgcn_sinf(ipB);
        const float c1B = c0B * cdB - s0B * sdB;
        const float s1B = s0B * cdB + c0B * sdB;
        const float c2B = c1B * cdB - s1B * sdB;
        const float c3B = c2B * cdB - (s1B * cdB + c1B * sdB) * sdB;
        const float r2B = 2.f * (1.f - 2.f * sdB * sdB);
        f32x2 DB_p = {wp.y * c0B, wp.y * c1B};
        f32x2 DB_c = {wp.y * c2B, wp.y * c3B};
        const f32x2 RB = {r2B, r2B};

        const float* zc = zrow + (size_t)j * 68;
#pragma unroll
        for (int m = 0; m < 8; ++m) {     // 8 x float4 = 32 k = 16 pairs
            float4 z4 = *(const float4*)(zc + 4 * m);
            f32x2 zlo = {z4.x, z4.y};
            f32x2 zhi = {z4.z, z4.w};
            accA[2 * m    ] += zlo * DA_p;
            accB[2 * m    ] += zlo * DB_p;
            f32x2 tA = RA * DA_c - DA_p;  DA_p = DA_c;  DA_c = tA;
            f32x2 tB = RB * DB_c - DB_p;  DB_p = DB_c;  DB_c = tB;
            accA[2 * m + 1] += zhi * DA_p;
            accB[2 * m + 1] += zhi * DB_p;
            tA = RA * DA_c - DA_p;  DA_p = DA_c;  DA_c = tA;
            tB = RB * DB_c - DB_p;  DB_p = DB_c;  DB_c = tB;
        }
    }

    short* Tpl = Tp + (size_t)blockIdx.z * (TOT * OD);
    const int ia = i0 + il;
    const int kb = k0 + kg * 32;
#pragma unroll
    for (int m = 0; m < 16; ++m) {
        *(uint*)(Tpl + (size_t)(kb + 2 * m    ) * OD + ia) = pack2(accA[m].x, accB[m].x);
        *(uint*)(Tpl + (size_t)(kb + 2 * m + 1) * OD + ia) = pack2(accA[m].y, accB[m].y);
    }
}

// ============ K2b: Wt[b][o][s] = bf16(Z + sum Tp) transposed ============
__global__ __launch_bounds__(256) void k2b_w(
    const float* __restrict__ Z, const short* __restrict__ Tp,
    short* __restrict__ Wt)
{
    __shared__ float tl[32][36];
    const int kt0 = blockIdx.x * 32;    // global k = b*1024+s
    const int o0  = blockIdx.y * 32;
    const int tid = threadIdx.x;
    const int r   = tid >> 3;           // 0..31 (kt row)
    const int c4  = (tid & 7) * 4;      // 0..28 (o col)

    const size_t idx = (size_t)(kt0 + r) * OD + o0 + c4;
    float4 z = *(const float4*)(Z + idx);
#pragma unroll
    for (int p = 0; p < JSPL; ++p) {
        uint2 t = *(const uint2*)(Tp + (size_t)p * (TOT * OD) + idx);
        z.x += __uint_as_float(t.x << 16);
        z.y += __uint_as_float(t.x & 0xFFFF0000u);
        z.z += __uint_as_float(t.y << 16);
        z.w += __uint_as_float(t.y & 0xFFFF0000u);
    }
    *(float4*)&tl[r][c4] = z;
    __syncthreads();

    const int ol = tid >> 3;            // 0..31 (o row out)
    const int sc = (tid & 7) * 4;       // 0..28 (s col out)
    const int b  = kt0 >> 10;
    const int sb = kt0 & 1023;
    uint lo = pack2(tl[sc + 0][ol], tl[sc + 1][ol]);
    uint hi = pack2(tl[sc + 2][ol], tl[sc + 3][ol]);
    *(uint2*)(Wt + ((size_t)b * OD + o0 + ol) * SEQL + sb + sc) = make_uint2(lo, hi);
}

// ============ K3: Op[ksp][b] = ALt * Wt_b^T (s-chunk ksp) ============
__global__ __launch_bounds__(256, 4) void k3_mfma(
    const short* __restrict__ ALt, const short* __restrict__ Wt,
    float* __restrict__ Op)
{
    const int b   = blockIdx.z & 1;
    const int ksp = blockIdx.z >> 1;
    mfma_tile64<false>(ALt, SEQL, Wt + (size_t)b * OD * SEQL, SEQL,
                       Op + (size_t)ksp * (NB * TQ * OD) + (size_t)b * TQ * OD, OD,
                       blockIdx.x * 64, blockIdx.y * 64, ksp * (SEQL / K3SPL), (SEQL / K3SPL) / 32);
}

// ============ K4: out = sum of 8 Op planes; write out_seq scalar ============
__global__ __launch_bounds__(256) void k4_comb(
    const float* __restrict__ Op, float* __restrict__ out, int out_size)
{
    const int m = blockIdx.x * 256 + threadIdx.x;   // float4 index
    const int N4 = (NB * TQ * OD) / 4;
    if (m < N4) {
        float4 a = ((const float4*)Op)[m];
#pragma unroll
        for (int p = 1; p < K3SPL; ++p) {
            float4 t = ((const float4*)(Op + (size_t)p * (NB * TQ * OD)))[m];
            a.x += t.x; a.y += t.y; a.z += t.z; a.w += t.w;
        }
        ((float4*)out)[m] = a;
    }
    if (m == 0 && out_size > NB * TQ * OD)
        out[NB * TQ * OD] = (float)TQ;   // second output: out_seq = 512
}

extern "C" void kernel_launch(void* const* d_in, const int* in_sizes, int n_in,
                              void* d_out, int out_size, void* d_ws, size_t ws_size,
                              hipStream_t stream)
{
    const float* x  = (const float*)d_in[0];
    const float* M  = (const float*)d_in[1];
    const float* P  = (const float*)d_in[2];
    const float* L  = (const float*)d_in[3];
    const float* g  = (const float*)d_in[4];
    const float* be = (const float*)d_in[5];
    float* out = (float*)d_out;

    float* ws_f = (float*)d_ws;
    float* Zp = ws_f;                               // 2 * TOT*OD f32
    float* Z  = Zp + 2 * (size_t)TOT * OD;          // TOT*OD f32
    float* Zn = Z  + (size_t)TOT * OD;              // TOT*OD f32
    float* Op = Zn + (size_t)TOT * OD;              // K3SPL * NB*TQ*OD f32
    short* ALt = (short*)(Op + (size_t)K3SPL * NB * TQ * OD);
    short* Wt  = ALt + (size_t)TQ * SEQL;
    short* Tp  = Wt  + (size_t)NB * OD * SEQL;      // JSPL * TOT*OD bf16

    k1_mfma<<<dim3(TOT / 64, OD / 64, 2), 256, 0, stream>>>(x, M, Zp);
    k1b_ln<<<768, 256, 0, stream>>>(Zp, g, be, Z, Zn, L, ALt);
    k2_t<<<dim3(TOT / 64, OD / 128, JSPL), 128, 0, stream>>>(Zn, P, Tp);
    k2b_w<<<dim3(TOT / 32, OD / 32), 256, 0, stream>>>(Z, Tp, Wt);
    k3_mfma<<<dim3(TQ / 64, OD / 64, NB * K3SPL), 256, 0, stream>>>(ALt, Wt, Op);
    k4_comb<<<(NB * TQ * OD / 4 + 255) / 256, 256, 0, stream>>>(Op, out, out_size);
}